// Round 6
// baseline (342.976 us; speedup 1.0000x reference)
//
#include <hip/hip_runtime.h>
#include <hip/hip_cooperative_groups.h>
#include <cstddef>

namespace cg = cooperative_groups;

#define TT 1024
#define DDIM 512
#define HH 8
#define NND 128          // interpolation nodes per (b,h)
#define NW 72            // node_out row width: 64 d + Z at [64], padded

typedef __attribute__((ext_vector_type(8))) short bfrag;   // 8 bf16 (4 VGPRs)
typedef __attribute__((ext_vector_type(4))) float facc;    // 4 fp32 acc

#define SC2   2.8853900817779268f   // 2*log2(e)
#define L2E   1.4426950408889634f

static __device__ __forceinline__ unsigned bfrne(float f) {
    unsigned u = __float_as_uint(f);
    return (u + 0x7fffu + ((u >> 16) & 1u)) >> 16;
}
static __device__ __forceinline__ unsigned pack2rne(float a, float b) {
    return bfrne(a) | (bfrne(b) << 16);
}
static __device__ __forceinline__ unsigned pack2hu(float a, float b) {
    return ((__float_as_uint(a) + 0x8000u) >> 16) |
           ((__float_as_uint(b) + 0x8000u) & 0xffff0000u);
}
static __device__ __forceinline__ void gl2lds16(const void* g, void* l) {
    __builtin_amdgcn_global_load_lds(
        (const __attribute__((address_space(1))) unsigned int*)g,
        (__attribute__((address_space(3))) unsigned int*)l, 16, 0, 0);
}
// w(z2) = exp(tanh(z)) with z2 = 2*log2e*z pre-scaled
static __device__ __forceinline__ float wfun(float z2) {
    float t = __builtin_amdgcn_exp2f(z2);
    float r = __builtin_amdgcn_rcpf(t + 1.f);
    return __builtin_amdgcn_exp2f(fmaf(r, -2.f * L2E, L2E));
}

// phase-shared LDS union (36.1 KB -> 1 block/CU, matches 256-block coop grid)
union SMem {
    float sT[64][65];                                          // P0 transpose
    unsigned short g1[12288];                                  // gemm1/gemm2: sA|sB; epi eT/yT
    struct { unsigned short kxT[64 * 256]; float ksc[1024]; float redl[8]; } at;
};

__global__ __launch_bounds__(256, 1) void mega_kernel(
    const float* __restrict__ x, const float* __restrict__ Wq,
    const float* __restrict__ bq, const float* __restrict__ Wk,
    const float* __restrict__ bk, const float* __restrict__ Wp,
    const float* __restrict__ bp, const float* __restrict__ wm,
    const float* __restrict__ ln_g, const float* __restrict__ ln_b,
    float* __restrict__ out,
    unsigned short* __restrict__ xb, unsigned short* __restrict__ WkT,
    unsigned short* __restrict__ WpT, unsigned short* __restrict__ vq2b,
    float* __restrict__ qsb2, unsigned short* __restrict__ kxTg,
    float* __restrict__ qs2, float* __restrict__ ks2,
    float* __restrict__ ndo, float* __restrict__ mn2,
    float* __restrict__ i127, unsigned short* __restrict__ attb,
    unsigned short* __restrict__ yb)
{
    __shared__ SMem sm;
    cg::grid_group grid = cg::this_grid();
    const int bid = blockIdx.x, tid = threadIdx.x;
    const int lane = tid & 63, wave = tid >> 6;
    const int l15 = lane & 15, quad = lane >> 4;

    // ================= P0: prepare (2192 tasks) =================
    for (int t = bid; t < 2192; t += 256) {
        if (t < 2048) {
            const int row = t * 4 + wave;
            const float4* xr = (const float4*)(x + (size_t)row * DDIM);
            float4 x0 = xr[lane * 2], x1 = xr[lane * 2 + 1];
            uint4 st;
            st.x = pack2rne(x0.x, x0.y); st.y = pack2rne(x0.z, x0.w);
            st.z = pack2rne(x1.x, x1.y); st.w = pack2rne(x1.z, x1.w);
            int p = lane ^ (row & 7);
            *(uint4*)(xb + (size_t)row * DDIM + p * 8) = st;
        } else if (t < 2176) {
            int idx = t - 2048;
            const float* src = (idx & 64) ? Wp : Wk;
            unsigned short* dst = (idx & 64) ? WpT : WkT;
            idx &= 63;
            const int n0 = (idx & 7) * 64, k0 = (idx >> 3) * 64;
            #pragma unroll
            for (int it = 0; it < 4; ++it) {
                int task = it * 256 + tid;
                int kr = task >> 4, c4 = (task & 15) * 4;
                float4 v = *(const float4*)(src + (size_t)(k0 + kr) * DDIM + n0 + c4);
                sm.sT[kr][c4] = v.x; sm.sT[kr][c4 + 1] = v.y;
                sm.sT[kr][c4 + 2] = v.z; sm.sT[kr][c4 + 3] = v.w;
            }
            __syncthreads();
            #pragma unroll
            for (int it = 0; it < 2; ++it) {
                int task = it * 256 + tid;
                int n = task >> 3, kg = task & 7;
                unsigned u[4];
                #pragma unroll
                for (int jj = 0; jj < 4; ++jj)
                    u[jj] = pack2rne(sm.sT[kg * 8 + jj * 2][n], sm.sT[kg * 8 + jj * 2 + 1][n]);
                int p = ((k0 >> 3) + kg) ^ (n & 7);
                uint4 st; st.x = u[0]; st.y = u[1]; st.z = u[2]; st.w = u[3];
                *(uint4*)(dst + (size_t)(n0 + n) * DDIM + p * 8) = st;
            }
            __syncthreads();   // sT reused next iteration
        } else {
            int idx = (t - 2176) * 256 + tid;   // 0..4095
            int h = idx >> 9, d = idx & 511;
            float s = 0.f;
            #pragma unroll 8
            for (int j = 0; j < 64; ++j)
                s = fmaf(Wq[(size_t)d * DDIM + h * 64 + j], wm[64 + j], s);
            vq2b[h * DDIM + d] = (unsigned short)bfrne(s * SC2);
            if (idx < HH) {
                float sb = 0.f;
                for (int j = 0; j < 64; ++j)
                    sb = fmaf(bq[idx * 64 + j], wm[64 + j], sb);
                qsb2[idx] = sb * SC2;
            }
        }
    }
    grid.sync();

    // ================= P1: gemm1 kx = xb @ WkT + bk (512 tasks) =================
    for (int t = bid; t < 512; t += 256) {
        const int h = t & 7, row0 = (t >> 3) * 128;
        const int col0 = h * 64;
        unsigned short* sA = sm.g1;
        unsigned short* sB = sm.g1 + 8192;

        facc acc[2][4]; facc accq[2];
        #pragma unroll
        for (int i = 0; i < 2; ++i) {
            #pragma unroll
            for (int j = 0; j < 4; ++j) { acc[i][j][0]=0.f; acc[i][j][1]=0.f; acc[i][j][2]=0.f; acc[i][j][3]=0.f; }
            accq[i][0]=0.f; accq[i][1]=0.f; accq[i][2]=0.f; accq[i][3]=0.f;
        }
        for (int k0 = 0; k0 < 512; k0 += 64) {
            #pragma unroll
            for (int it = 0; it < 4; ++it) {
                int g = it * 256 + tid;
                int r = g >> 3, kg = g & 7;
                gl2lds16(xb + (size_t)(row0 + r) * 512 + k0 + kg * 8, &sA[g * 8]);
            }
            #pragma unroll
            for (int it = 0; it < 2; ++it) {
                int g = it * 256 + tid;
                int r = g >> 3, kg = g & 7;
                gl2lds16(WkT + (size_t)(col0 + r) * 512 + k0 + kg * 8, &sB[g * 8]);
            }
            __syncthreads();
            #pragma unroll
            for (int ks_ = 0; ks_ < 2; ++ks_) {
                int slot = (ks_ * 4 + quad) ^ (l15 & 7);
                bfrag a[2], b[4];
                #pragma unroll
                for (int i = 0; i < 2; ++i)
                    a[i] = *(const bfrag*)&sA[(wave * 32 + i * 16 + l15) * 64 + slot * 8];
                #pragma unroll
                for (int nt = 0; nt < 4; ++nt)
                    b[nt] = *(const bfrag*)&sB[(nt * 16 + l15) * 64 + slot * 8];
                bfrag bvq = *(const bfrag*)(vq2b + h * 512 + k0 + ks_ * 32 + quad * 8);
                #pragma unroll
                for (int i = 0; i < 2; ++i) {
                    #pragma unroll
                    for (int nt = 0; nt < 4; ++nt)
                        acc[i][nt] = __builtin_amdgcn_mfma_f32_16x16x32_bf16(a[i], b[nt], acc[i][nt], 0, 0, 0);
                    accq[i] = __builtin_amdgcn_mfma_f32_16x16x32_bf16(a[i], bvq, accq[i], 0, 0, 0);
                }
            }
            __syncthreads();
        }
        // epilogue
        const int bb = row0 >> 10, t0 = row0 & 1023;
        const float qsbh = qsb2[h];
        float bvv[4], wmv[4];
        #pragma unroll
        for (int nt = 0; nt < 4; ++nt) {
            bvv[nt] = bk[col0 + nt * 16 + l15];
            wmv[nt] = wm[nt * 16 + l15] * SC2;
        }
        float part[2][4];
        #pragma unroll
        for (int i = 0; i < 2; ++i)
            #pragma unroll
            for (int r = 0; r < 4; ++r) part[i][r] = 0.f;
        unsigned short* eT = sm.g1;   // [d][t] stride 136
        #pragma unroll
        for (int i = 0; i < 2; ++i) {
            int tr = wave * 32 + i * 16 + quad * 4;
            #pragma unroll
            for (int nt = 0; nt < 4; ++nt) {
                int col = nt * 16 + l15;
                float v0 = acc[i][nt][0] + bvv[nt], v1 = acc[i][nt][1] + bvv[nt];
                float v2 = acc[i][nt][2] + bvv[nt], v3 = acc[i][nt][3] + bvv[nt];
                part[i][0] = fmaf(wmv[nt], v0, part[i][0]);
                part[i][1] = fmaf(wmv[nt], v1, part[i][1]);
                part[i][2] = fmaf(wmv[nt], v2, part[i][2]);
                part[i][3] = fmaf(wmv[nt], v3, part[i][3]);
                *(unsigned*)&eT[col * 136 + tr]     = pack2rne(v0, v1);
                *(unsigned*)&eT[col * 136 + tr + 2] = pack2rne(v2, v3);
            }
        }
        #pragma unroll
        for (int i = 0; i < 2; ++i)
            #pragma unroll
            for (int r = 0; r < 4; ++r) {
                float p = part[i][r];
                p += __shfl_xor(p, 1); p += __shfl_xor(p, 2);
                p += __shfl_xor(p, 4); p += __shfl_xor(p, 8);
                if (l15 == 0) {
                    size_t o = (size_t)(bb * HH + h) * TT + t0 + wave * 32 + i * 16 + quad * 4 + r;
                    ks2[o] = p;
                    qs2[o] = accq[i][r] + qsbh;
                }
            }
        __syncthreads();
        unsigned short* kxbase = kxTg + ((size_t)(bb * HH + h) * 64) * TT;
        #pragma unroll
        for (int it = 0; it < 4; ++it) {
            int task = it * 256 + tid;
            int col = task >> 4, seg = task & 15;
            uint4 v = *(const uint4*)&eT[col * 136 + seg * 8];
            int g = (t0 >> 3) + seg;
            int p = g ^ (col & 7);
            *(uint4*)(kxbase + (size_t)col * TT + p * 8) = v;
        }
        __syncthreads();   // eT reused next iteration
    }
    grid.sync();

    // ================= P2: attention node curves (256 tasks) =================
    {
        const int t = bid;                  // exactly one task per block
        const int bh = t >> 2, nh = (t >> 1) & 1, ckh = t & 1;
        ((float4*)sm.at.ksc)[tid] = ((const float4*)(ks2 + (size_t)bh * TT))[tid];
        float4 q4 = ((const float4*)(qs2 + (size_t)bh * TT))[tid];
        float mn = fminf(fminf(q4.x, q4.y), fminf(q4.z, q4.w));
        float mx = fmaxf(fmaxf(q4.x, q4.y), fmaxf(q4.z, q4.w));
        #pragma unroll
        for (int off = 32; off > 0; off >>= 1) {
            mn = fminf(mn, __shfl_xor(mn, off));
            mx = fmaxf(mx, __shfl_xor(mx, off));
        }
        if (lane == 0) { sm.at.redl[wave] = mn; sm.at.redl[4 + wave] = mx; }
        __syncthreads();
        const float mnv = fminf(fminf(sm.at.redl[0], sm.at.redl[1]), fminf(sm.at.redl[2], sm.at.redl[3]));
        const float mxv = fmaxf(fmaxf(sm.at.redl[4], sm.at.redl[5]), fmaxf(sm.at.redl[6], sm.at.redl[7]));
        if (tid == 0 && nh == 0 && ckh == 0) {
            mn2[bh] = mnv;
            i127[bh] = 127.f / fmaxf(mxv - mnv, 1e-12f);
        }
        const float h2v = (mxv - mnv) * (1.f / 127.f);
        const float zA = mnv + (nh * 64 + wave * 16 + l15) * h2v;

        const unsigned short* kxbase = kxTg + (size_t)bh * 64 * TT;
        facc acc[4]; facc accZ;
        #pragma unroll
        for (int i = 0; i < 4; ++i) { acc[i][0]=0.f; acc[i][1]=0.f; acc[i][2]=0.f; acc[i][3]=0.f; }
        accZ[0]=0.f; accZ[1]=0.f; accZ[2]=0.f; accZ[3]=0.f;
        bfrag ones;
        #pragma unroll
        for (int j = 0; j < 8; ++j) ones[j] = (short)0x3F80;

        #pragma unroll
        for (int cc = 0; cc < 2; ++cc) {
            const int ck = ckh * 2 + cc;
            #pragma unroll
            for (int it = 0; it < 8; ++it) {
                int g = it * 256 + tid;
                int d = g >> 5, j = g & 31;
                gl2lds16(kxbase + (size_t)d * TT + ck * 256 + j * 8, &sm.at.kxT[g * 8]);
            }
            __syncthreads();
            #pragma unroll
            for (int kst = 0; kst < 8; ++kst) {
                const float* kvp = &sm.at.ksc[ck * 256 + kst * 32 + quad * 8];
                float4 kv0 = *(const float4*)kvp;
                float4 kv1 = *(const float4*)(kvp + 4);
                int slot = (kst * 4 + quad) ^ (l15 & 7);
                union { unsigned u[4]; bfrag f; } afu;
                afu.u[0] = pack2hu(wfun(zA + kv0.x), wfun(zA + kv0.y));
                afu.u[1] = pack2hu(wfun(zA + kv0.z), wfun(zA + kv0.w));
                afu.u[2] = pack2hu(wfun(zA + kv1.x), wfun(zA + kv1.y));
                afu.u[3] = pack2hu(wfun(zA + kv1.z), wfun(zA + kv1.w));
                #pragma unroll
                for (int dt = 0; dt < 4; ++dt) {
                    bfrag bf_ = *(const bfrag*)&sm.at.kxT[(dt * 16 + l15) * 256 + slot * 8];
                    acc[dt] = __builtin_amdgcn_mfma_f32_16x16x32_bf16(afu.f, bf_, acc[dt], 0, 0, 0);
                }
                accZ = __builtin_amdgcn_mfma_f32_16x16x32_bf16(afu.f, ones, accZ, 0, 0, 0);
            }
            __syncthreads();
        }
        float* ob = ndo + ((size_t)(ckh * 64 + bh) * NND) * NW;
        #pragma unroll
        for (int r = 0; r < 4; ++r) {
            int node = nh * 64 + wave * 16 + quad * 4 + r;
            #pragma unroll
            for (int dt = 0; dt < 4; ++dt)
                ob[(size_t)node * NW + dt * 16 + l15] = acc[dt][r];
            if (l15 == 0) ob[(size_t)node * NW + 64] = accZ[r];
        }
    }
    grid.sync();

    // ================= P3: cubic interpolation (2048 tasks) =================
    for (int t = bid; t < 2048; t += 256) {
        const int row = t * 4 + wave;
        const int b = row >> 10, tt = row & 1023;
        const int hh2 = lane >> 5, dp = lane & 31;
        #pragma unroll
        for (int h0 = 0; h0 < 8; h0 += 2) {
            const int hh = h0 + hh2;
            const int bh = b * HH + hh;
            float qv = qs2[(size_t)bh * TT + tt];
            float u = (qv - mn2[bh]) * i127[bh];
            int i = (int)floorf(u) - 1;
            i = i < 0 ? 0 : (i > NND - 4 ? NND - 4 : i);
            float s = u - (float)i;
            float s1 = s - 1.f, s2 = s - 2.f, s3 = s - 3.f;
            float w0 = -s1 * s2 * s3 * (1.f / 6.f);
            float w1 = s * s2 * s3 * 0.5f;
            float w2 = -s * s1 * s3 * 0.5f;
            float w3 = s * s1 * s2 * (1.f / 6.f);
            const float* b0p = ndo + ((size_t)bh * NND + i) * NW;
            const float* b1p = ndo + ((size_t)(64 + bh) * NND + i) * NW;
            float nx = 0.f, ny = 0.f, zz = 0.f;
            #pragma unroll
            for (int c = 0; c < 2; ++c) {
                const float* base = c ? b1p : b0p;
                float2 v0 = *(const float2*)(base + 2 * dp);
                float2 v1 = *(const float2*)(base + NW + 2 * dp);
                float2 v2 = *(const float2*)(base + 2 * NW + 2 * dp);
                float2 v3 = *(const float2*)(base + 3 * NW + 2 * dp);
                nx += w0 * v0.x + w1 * v1.x + w2 * v2.x + w3 * v3.x;
                ny += w0 * v0.y + w1 * v1.y + w2 * v2.y + w3 * v3.y;
                zz += w0 * base[64] + w1 * base[NW + 64] + w2 * base[2 * NW + 64] + w3 * base[3 * NW + 64];
            }
            float rz = __builtin_amdgcn_rcpf(zz);
            unsigned pk = pack2rne(nx * rz, ny * rz);
            int col = hh * 64 + 2 * dp;
            int p = (col >> 3) ^ (row & 7);
            *(unsigned*)&attb[(size_t)row * DDIM + p * 8 + (col & 7)] = pk;
        }
    }
    grid.sync();

    // ================= P4: gemm2 y = x + attb @ WpT + bp (512 tasks) ==========
    for (int t = bid; t < 512; t += 256) {
        const int col0 = (t & 7) * 64, row0 = (t >> 3) * 128;
        unsigned short* sA = sm.g1;
        unsigned short* sB = sm.g1 + 8192;
        facc acc[2][4];
        #pragma unroll
        for (int i = 0; i < 2; ++i)
            #pragma unroll
            for (int j = 0; j < 4; ++j) { acc[i][j][0]=0.f; acc[i][j][1]=0.f; acc[i][j][2]=0.f; acc[i][j][3]=0.f; }
        for (int k0 = 0; k0 < 512; k0 += 64) {
            #pragma unroll
            for (int it = 0; it < 4; ++it) {
                int g = it * 256 + tid;
                int r = g >> 3, kg = g & 7;
                gl2lds16(attb + (size_t)(row0 + r) * 512 + k0 + kg * 8, &sA[g * 8]);
            }
            #pragma unroll
            for (int it = 0; it < 2; ++it) {
                int g = it * 256 + tid;
                int r = g >> 3, kg = g & 7;
                gl2lds16(WpT + (size_t)(col0 + r) * 512 + k0 + kg * 8, &sB[g * 8]);
            }
            __syncthreads();
            #pragma unroll
            for (int ks_ = 0; ks_ < 2; ++ks_) {
                int slot = (ks_ * 4 + quad) ^ (l15 & 7);
                bfrag a[2], b[4];
                #pragma unroll
                for (int i = 0; i < 2; ++i)
                    a[i] = *(const bfrag*)&sA[(wave * 32 + i * 16 + l15) * 64 + slot * 8];
                #pragma unroll
                for (int nt = 0; nt < 4; ++nt)
                    b[nt] = *(const bfrag*)&sB[(nt * 16 + l15) * 64 + slot * 8];
                #pragma unroll
                for (int i = 0; i < 2; ++i)
                    #pragma unroll
                    for (int nt = 0; nt < 4; ++nt)
                        acc[i][nt] = __builtin_amdgcn_mfma_f32_16x16x32_bf16(a[i], b[nt], acc[i][nt], 0, 0, 0);
            }
            __syncthreads();
        }
        float bvv[4];
        #pragma unroll
        for (int nt = 0; nt < 4; ++nt) bvv[nt] = bp[col0 + nt * 16 + l15];
        unsigned short* yT = sm.g1;   // [row][col] stride 72
        #pragma unroll
        for (int i = 0; i < 2; ++i) {
            #pragma unroll
            for (int nt = 0; nt < 4; ++nt) {
                int col = nt * 16 + l15;
                #pragma unroll
                for (int r = 0; r < 4; ++r) {
                    int row = wave * 32 + i * 16 + quad * 4 + r;
                    float xv = x[(size_t)(row0 + row) * DDIM + col0 + col];
                    float y = acc[i][nt][r] + bvv[nt] + xv;
                    yT[row * 72 + col] = (unsigned short)bfrne(y);
                }
            }
        }
        __syncthreads();
        #pragma unroll
        for (int it = 0; it < 4; ++it) {
            int task = it * 256 + tid;
            int row = task >> 3, seg = task & 7;
            uint4 v = *(const uint4*)&yT[row * 72 + seg * 8];
            *(uint4*)(yb + (size_t)(row0 + row) * DDIM + col0 + seg * 8) = v;
        }
        __syncthreads();   // yT reused next iteration
    }
    grid.sync();

    // ================= P5: LayerNorm (2048 tasks) =================
    for (int t = bid; t < 2048; t += 256) {
        const int row = t * 4 + wave;
        uint4 v = *(const uint4*)(yb + (size_t)row * DDIM + lane * 8);
        float y[8];
        y[0] = __uint_as_float(v.x << 16); y[1] = __uint_as_float(v.x & 0xffff0000u);
        y[2] = __uint_as_float(v.y << 16); y[3] = __uint_as_float(v.y & 0xffff0000u);
        y[4] = __uint_as_float(v.z << 16); y[5] = __uint_as_float(v.z & 0xffff0000u);
        y[6] = __uint_as_float(v.w << 16); y[7] = __uint_as_float(v.w & 0xffff0000u);
        float s = 0.f, s2 = 0.f;
        #pragma unroll
        for (int i = 0; i < 8; ++i) { s += y[i]; s2 = fmaf(y[i], y[i], s2); }
        #pragma unroll
        for (int off = 32; off > 0; off >>= 1) {
            s += __shfl_xor(s, off);
            s2 += __shfl_xor(s2, off);
        }
        float mu = s * (1.f / 512.f);
        float var = s2 * (1.f / 512.f) - mu * mu;
        float inv = rsqrtf(var + 1e-5f);
        const float4* gp = (const float4*)(ln_g + lane * 8);
        const float4* bpt = (const float4*)(ln_b + lane * 8);
        float4 g0 = gp[0], g1 = gp[1], b0 = bpt[0], b1 = bpt[1];
        float4 o0, o1;
        o0.x = (y[0] - mu) * inv * g0.x + b0.x; o0.y = (y[1] - mu) * inv * g0.y + b0.y;
        o0.z = (y[2] - mu) * inv * g0.z + b0.z; o0.w = (y[3] - mu) * inv * g0.w + b0.w;
        o1.x = (y[4] - mu) * inv * g1.x + b1.x; o1.y = (y[5] - mu) * inv * g1.y + b1.y;
        o1.z = (y[6] - mu) * inv * g1.z + b1.z; o1.w = (y[7] - mu) * inv * g1.w + b1.w;
        float4* op = (float4*)(out + (size_t)row * DDIM);
        op[lane * 2] = o0; op[lane * 2 + 1] = o1;
    }
}

// ---- launch -------------------------------------------------------------------
extern "C" void kernel_launch(void* const* d_in, const int* in_sizes, int n_in,
                              void* d_out, int out_size, void* d_ws, size_t ws_size,
                              hipStream_t stream)
{
    const float* x    = (const float*)d_in[0];
    const float* Wq   = (const float*)d_in[1];
    const float* bq   = (const float*)d_in[2];
    const float* Wk   = (const float*)d_in[3];
    const float* bk   = (const float*)d_in[4];
    const float* Wp   = (const float*)d_in[5];
    const float* bp   = (const float*)d_in[6];
    const float* wm   = (const float*)d_in[7];
    const float* ln_g = (const float*)d_in[8];
    const float* ln_b = (const float*)d_in[9];
    float* out = (float*)d_out;

    float* ws = (float*)d_ws;
    float*          qsb2 = ws;                                    // 64
    unsigned short* vq2b = (unsigned short*)(ws + 64);            // 2048 f
    unsigned short* WkT  = (unsigned short*)(ws + 2112);          // 131072 f
    unsigned short* WpT  = (unsigned short*)(ws + 133184);        // 131072 f
    unsigned short* xb   = (unsigned short*)(ws + 264256);        // 2097152 f
    unsigned short* kxTg = (unsigned short*)(ws + 2361408);       // 2097152 f
    float*          qs2  = ws + 4458560;                          // 65536
    float*          ks2  = ws + 4524096;                          // 65536
    unsigned short* attb = (unsigned short*)(ws + 4589632);       // 2097152 f
    float*          ndo  = ws + 6686784;                          // 1179648 (2 partials)
    float*          mn2  = ws + 7866432;                          // 64
    float*          i127 = ws + 7866496;                          // 64
    unsigned short* yb   = xb;   // xb dead after P1; reuse for y

    void* args[] = {
        (void*)&x, (void*)&Wq, (void*)&bq, (void*)&Wk, (void*)&bk,
        (void*)&Wp, (void*)&bp, (void*)&wm, (void*)&ln_g, (void*)&ln_b,
        (void*)&out, (void*)&xb, (void*)&WkT, (void*)&WpT, (void*)&vq2b,
        (void*)&qsb2, (void*)&kxTg, (void*)&qs2, (void*)&ks2, (void*)&ndo,
        (void*)&mn2, (void*)&i127, (void*)&attb, (void*)&yb
    };
    hipLaunchCooperativeKernel((void*)mega_kernel, dim3(256), dim3(256),
                               args, 0, stream);
}

// Round 7
// 153.126 us; speedup vs baseline: 2.2398x; 2.2398x over previous
//
#include <hip/hip_runtime.h>
#include <cstddef>

#define TT 1024
#define DDIM 512
#define HH 8
#define NND 128          // interpolation nodes per (b,h)
#define NS 68            // node LDS row stride (floats): 64 d + Z at [64], 16B-aligned

typedef __attribute__((ext_vector_type(8))) short bfrag;   // 8 bf16 (4 VGPRs)
typedef __attribute__((ext_vector_type(4))) float facc;    // 4 fp32 acc

#define SC2   2.8853900817779268f   // 2*log2(e)
#define L2E   1.4426950408889634f

static __device__ __forceinline__ unsigned bfrne(float f) {
    unsigned u = __float_as_uint(f);
    return (u + 0x7fffu + ((u >> 16) & 1u)) >> 16;
}
static __device__ __forceinline__ unsigned pack2rne(float a, float b) {
    return bfrne(a) | (bfrne(b) << 16);
}
static __device__ __forceinline__ unsigned pack2hu(float a, float b) {
    return ((__float_as_uint(a) + 0x8000u) >> 16) |
           ((__float_as_uint(b) + 0x8000u) & 0xffff0000u);
}
static __device__ __forceinline__ void gl2lds16(const void* g, void* l) {
    __builtin_amdgcn_global_load_lds(
        (const __attribute__((address_space(1))) unsigned int*)g,
        (__attribute__((address_space(3))) unsigned int*)l, 16, 0, 0);
}
// w(z2) = exp(tanh(z)) with z2 = 2*log2e*z pre-scaled
static __device__ __forceinline__ float wfun(float z2) {
    float t = __builtin_amdgcn_exp2f(z2);
    float r = __builtin_amdgcn_rcpf(t + 1.f);
    return __builtin_amdgcn_exp2f(fmaf(r, -2.f * L2E, L2E));
}

// ---- K1: fused prepare ---------------------------------------------------------
// blocks [0,2048): x -> xb bf16 swizzled
// blocks [2048,2176): Wk/Wp -> WkT/WpT [n][k] bf16 swizzled
// blocks [2176,2192): vq2b[h][k] = bf16((Wq[:,h*64:]@wm[64:])*SC2); qsb2
__global__ __launch_bounds__(256) void prepare_kernel(
    const float* __restrict__ x, const float* __restrict__ Wk,
    const float* __restrict__ Wp, const float* __restrict__ Wq,
    const float* __restrict__ bq, const float* __restrict__ wm,
    unsigned short* __restrict__ xb, unsigned short* __restrict__ WkT,
    unsigned short* __restrict__ WpT, unsigned short* __restrict__ vq2b,
    float* __restrict__ qsb2)
{
    const int bx = blockIdx.x, tid = threadIdx.x;
    if (bx < 2048) {
        const int lane = tid & 63, wave = tid >> 6;
        const int row = bx * 4 + wave;
        const float4* xr = (const float4*)(x + (size_t)row * DDIM);
        float4 x0 = xr[lane * 2], x1 = xr[lane * 2 + 1];
        uint4 st;
        st.x = pack2rne(x0.x, x0.y); st.y = pack2rne(x0.z, x0.w);
        st.z = pack2rne(x1.x, x1.y); st.w = pack2rne(x1.z, x1.w);
        int p = lane ^ (row & 7);
        *(uint4*)(xb + (size_t)row * DDIM + p * 8) = st;
    } else if (bx < 2176) {
        int idx = bx - 2048;
        const float* src = (idx & 64) ? Wp : Wk;
        unsigned short* dst = (idx & 64) ? WpT : WkT;
        idx &= 63;
        const int n0 = (idx & 7) * 64, k0 = (idx >> 3) * 64;
        __shared__ float sT[64][65];
        #pragma unroll
        for (int it = 0; it < 4; ++it) {
            int task = it * 256 + tid;
            int kr = task >> 4, c4 = (task & 15) * 4;
            float4 v = *(const float4*)(src + (size_t)(k0 + kr) * DDIM + n0 + c4);
            sT[kr][c4] = v.x; sT[kr][c4 + 1] = v.y; sT[kr][c4 + 2] = v.z; sT[kr][c4 + 3] = v.w;
        }
        __syncthreads();
        #pragma unroll
        for (int it = 0; it < 2; ++it) {
            int task = it * 256 + tid;
            int n = task >> 3, kg = task & 7;
            unsigned u[4];
            #pragma unroll
            for (int jj = 0; jj < 4; ++jj)
                u[jj] = pack2rne(sT[kg * 8 + jj * 2][n], sT[kg * 8 + jj * 2 + 1][n]);
            int p = ((k0 >> 3) + kg) ^ (n & 7);
            uint4 st; st.x = u[0]; st.y = u[1]; st.z = u[2]; st.w = u[3];
            *(uint4*)(dst + (size_t)(n0 + n) * DDIM + p * 8) = st;
        }
    } else {
        int idx = (bx - 2176) * 256 + tid;   // 0..4095
        int h = idx >> 9, d = idx & 511;
        float s = 0.f;
        #pragma unroll 8
        for (int j = 0; j < 64; ++j)
            s = fmaf(Wq[(size_t)d * DDIM + h * 64 + j], wm[64 + j], s);
        vq2b[h * DDIM + d] = (unsigned short)bfrne(s * SC2);
        if (idx < HH) {
            float sb = 0.f;
            for (int j = 0; j < 64; ++j)
                sb = fmaf(bq[idx * 64 + j], wm[64 + j], sb);
            qsb2[idx] = sb * SC2;
        }
    }
}

// ---- K2: GEMM1 kx = xb @ WkT + bk. Tile 128 t x 64 d (one head), BK=64. -------
// Fused: qs2 via extra MFMA with vq2b B-frag; ks2 reduction; kxT transpose.
__global__ __launch_bounds__(256) void gemm1_kernel(
    const unsigned short* __restrict__ A, const unsigned short* __restrict__ B,
    const float* __restrict__ bias, unsigned short* __restrict__ kxTg,
    float* __restrict__ ks2, const float* __restrict__ wm,
    const unsigned short* __restrict__ vq2b, const float* __restrict__ qsb2,
    float* __restrict__ qs2)
{
    __shared__ __align__(16) unsigned short smem[12288];   // sA 8192 | sB 4096
    unsigned short* sA = smem;
    unsigned short* sB = smem + 8192;
    const int tid = threadIdx.x, lane = tid & 63, wave = tid >> 6;
    const int l15 = lane & 15, quad = lane >> 4;
    const int h = blockIdx.x, row0 = blockIdx.y * 128;
    const int col0 = h * 64;

    facc acc[2][4]; facc accq[2];
    #pragma unroll
    for (int i = 0; i < 2; ++i) {
        #pragma unroll
        for (int j = 0; j < 4; ++j) { acc[i][j][0]=0.f; acc[i][j][1]=0.f; acc[i][j][2]=0.f; acc[i][j][3]=0.f; }
        accq[i][0]=0.f; accq[i][1]=0.f; accq[i][2]=0.f; accq[i][3]=0.f;
    }

    for (int k0 = 0; k0 < 512; k0 += 64) {
        #pragma unroll
        for (int it = 0; it < 4; ++it) {
            int g = it * 256 + tid;
            int r = g >> 3, kg = g & 7;
            gl2lds16(A + (size_t)(row0 + r) * 512 + k0 + kg * 8, &sA[g * 8]);
        }
        #pragma unroll
        for (int it = 0; it < 2; ++it) {
            int g = it * 256 + tid;
            int r = g >> 3, kg = g & 7;
            gl2lds16(B + (size_t)(col0 + r) * 512 + k0 + kg * 8, &sB[g * 8]);
        }
        __syncthreads();
        #pragma unroll
        for (int ks_ = 0; ks_ < 2; ++ks_) {
            int slot = (ks_ * 4 + quad) ^ (l15 & 7);
            bfrag a[2], b[4];
            #pragma unroll
            for (int i = 0; i < 2; ++i)
                a[i] = *(const bfrag*)&sA[(wave * 32 + i * 16 + l15) * 64 + slot * 8];
            #pragma unroll
            for (int nt = 0; nt < 4; ++nt)
                b[nt] = *(const bfrag*)&sB[(nt * 16 + l15) * 64 + slot * 8];
            bfrag bvq = *(const bfrag*)(vq2b + h * 512 + k0 + ks_ * 32 + quad * 8);
            #pragma unroll
            for (int i = 0; i < 2; ++i) {
                #pragma unroll
                for (int nt = 0; nt < 4; ++nt)
                    acc[i][nt] = __builtin_amdgcn_mfma_f32_16x16x32_bf16(a[i], b[nt], acc[i][nt], 0, 0, 0);
                accq[i] = __builtin_amdgcn_mfma_f32_16x16x32_bf16(a[i], bvq, accq[i], 0, 0, 0);
            }
        }
        __syncthreads();
    }

    const int bb = row0 >> 10, t0 = row0 & 1023;
    const float qsbh = qsb2[h];
    float bvv[4], wmv[4];
    #pragma unroll
    for (int nt = 0; nt < 4; ++nt) {
        bvv[nt] = bias[col0 + nt * 16 + l15];
        wmv[nt] = wm[nt * 16 + l15] * SC2;
    }
    float part[2][4];
    #pragma unroll
    for (int i = 0; i < 2; ++i)
        #pragma unroll
        for (int r = 0; r < 4; ++r) part[i][r] = 0.f;

    unsigned short* eT = smem;   // [d][t] stride 136
    #pragma unroll
    for (int i = 0; i < 2; ++i) {
        int tr = wave * 32 + i * 16 + quad * 4;
        #pragma unroll
        for (int nt = 0; nt < 4; ++nt) {
            int col = nt * 16 + l15;
            float v0 = acc[i][nt][0] + bvv[nt], v1 = acc[i][nt][1] + bvv[nt];
            float v2 = acc[i][nt][2] + bvv[nt], v3 = acc[i][nt][3] + bvv[nt];
            part[i][0] = fmaf(wmv[nt], v0, part[i][0]);
            part[i][1] = fmaf(wmv[nt], v1, part[i][1]);
            part[i][2] = fmaf(wmv[nt], v2, part[i][2]);
            part[i][3] = fmaf(wmv[nt], v3, part[i][3]);
            *(unsigned*)&eT[col * 136 + tr]     = pack2rne(v0, v1);
            *(unsigned*)&eT[col * 136 + tr + 2] = pack2rne(v2, v3);
        }
    }
    #pragma unroll
    for (int i = 0; i < 2; ++i)
        #pragma unroll
        for (int r = 0; r < 4; ++r) {
            float p = part[i][r];
            p += __shfl_xor(p, 1); p += __shfl_xor(p, 2);
            p += __shfl_xor(p, 4); p += __shfl_xor(p, 8);
            if (l15 == 0) {
                size_t o = (size_t)(bb * HH + h) * TT + t0 + wave * 32 + i * 16 + quad * 4 + r;
                ks2[o] = p;
                qs2[o] = accq[i][r] + qsbh;
            }
        }
    __syncthreads();
    unsigned short* kxbase = kxTg + ((size_t)(bb * HH + h) * 64) * TT;
    #pragma unroll
    for (int it = 0; it < 4; ++it) {
        int task = it * 256 + tid;
        int col = task >> 4, seg = task & 15;
        uint4 v = *(const uint4*)&eT[col * 136 + seg * 8];
        int g = (t0 >> 3) + seg;
        int p = g ^ (col & 7);
        *(uint4*)(kxbase + (size_t)col * TT + p * 8) = v;
    }
}

// ---- K3: node-curve attention + fused cubic interp ----------------------------
// grid 128: (bh, t-half). Nodes computed identically per bh-pair (deterministic),
// kept in LDS; each block interpolates its 512-row t-range -> attb.
__global__ __launch_bounds__(256) void attn_kernel(
    const unsigned short* __restrict__ kxTg, const float* __restrict__ qs2,
    const float* __restrict__ ks2, unsigned short* __restrict__ attb)
{
    __shared__ __align__(16) unsigned short kxT[64 * 256];  // 32 KB
    __shared__ float ksc[1024];
    __shared__ float redl[8];
    __shared__ __align__(16) float nodes[NND * NS];         // 34 KB
    const int bh = blockIdx.x >> 1, thalf = blockIdx.x & 1;
    const int b = bh >> 3, h = bh & 7;
    const int tid = threadIdx.x, lane = tid & 63, wave = tid >> 6;
    const int l15 = lane & 15, quad = lane >> 4;

    ((float4*)ksc)[tid] = ((const float4*)(ks2 + (size_t)bh * TT))[tid];
    float4 q4 = ((const float4*)(qs2 + (size_t)bh * TT))[tid];
    float mn = fminf(fminf(q4.x, q4.y), fminf(q4.z, q4.w));
    float mx = fmaxf(fmaxf(q4.x, q4.y), fmaxf(q4.z, q4.w));
    #pragma unroll
    for (int off = 32; off > 0; off >>= 1) {
        mn = fminf(mn, __shfl_xor(mn, off));
        mx = fmaxf(mx, __shfl_xor(mx, off));
    }
    if (lane == 0) { redl[wave] = mn; redl[4 + wave] = mx; }
    __syncthreads();
    const float mnv = fminf(fminf(redl[0], redl[1]), fminf(redl[2], redl[3]));
    const float mxv = fmaxf(fmaxf(redl[4], redl[5]), fmaxf(redl[6], redl[7]));
    const float h2v = (mxv - mnv) * (1.f / 127.f);
    const float inv127v = 127.f / fmaxf(mxv - mnv, 1e-12f);
    const float zA = mnv + (wave * 16 + l15) * h2v;
    const float zB = zA + 64.f * h2v;

    const unsigned short* kxbase = kxTg + (size_t)bh * 64 * TT;
    facc acc[2][4]; facc accZ[2];
    #pragma unroll
    for (int g = 0; g < 2; ++g) {
        #pragma unroll
        for (int i = 0; i < 4; ++i) { acc[g][i][0]=0.f; acc[g][i][1]=0.f; acc[g][i][2]=0.f; acc[g][i][3]=0.f; }
        accZ[g][0]=0.f; accZ[g][1]=0.f; accZ[g][2]=0.f; accZ[g][3]=0.f;
    }
    bfrag ones;
    #pragma unroll
    for (int j = 0; j < 8; ++j) ones[j] = (short)0x3F80;

    for (int ck = 0; ck < 4; ++ck) {
        #pragma unroll
        for (int it = 0; it < 8; ++it) {
            int g = it * 256 + tid;
            int d = g >> 5, j = g & 31;
            gl2lds16(kxbase + (size_t)d * TT + ck * 256 + j * 8, &kxT[g * 8]);
        }
        __syncthreads();
        #pragma unroll
        for (int kst = 0; kst < 8; ++kst) {
            const float* kvp = &ksc[ck * 256 + kst * 32 + quad * 8];
            float4 kv0 = *(const float4*)kvp;
            float4 kv1 = *(const float4*)(kvp + 4);
            int slot = (kst * 4 + quad) ^ (l15 & 7);
            bfrag bf_[4];
            #pragma unroll
            for (int dt = 0; dt < 4; ++dt)
                bf_[dt] = *(const bfrag*)&kxT[(dt * 16 + l15) * 256 + slot * 8];
            #pragma unroll
            for (int g = 0; g < 2; ++g) {
                float z = g ? zB : zA;
                union { unsigned u[4]; bfrag f; } afu;
                afu.u[0] = pack2hu(wfun(z + kv0.x), wfun(z + kv0.y));
                afu.u[1] = pack2hu(wfun(z + kv0.z), wfun(z + kv0.w));
                afu.u[2] = pack2hu(wfun(z + kv1.x), wfun(z + kv1.y));
                afu.u[3] = pack2hu(wfun(z + kv1.z), wfun(z + kv1.w));
                #pragma unroll
                for (int dt = 0; dt < 4; ++dt)
                    acc[g][dt] = __builtin_amdgcn_mfma_f32_16x16x32_bf16(afu.f, bf_[dt], acc[g][dt], 0, 0, 0);
                accZ[g] = __builtin_amdgcn_mfma_f32_16x16x32_bf16(afu.f, ones, accZ[g], 0, 0, 0);
            }
        }
        __syncthreads();
    }
    // nodes -> LDS
    #pragma unroll
    for (int g = 0; g < 2; ++g) {
        #pragma unroll
        for (int r = 0; r < 4; ++r) {
            int node = g * 64 + wave * 16 + quad * 4 + r;
            #pragma unroll
            for (int dt = 0; dt < 4; ++dt)
                nodes[node * NS + dt * 16 + l15] = acc[g][dt][r];
            if (l15 == 0) nodes[node * NS + 64] = accZ[g][r];
        }
    }
    __syncthreads();

    // fused interp: 512 t x 16 dp tasks (4 cols each) = 8192 tasks, 32 iters
    const float* qsp = qs2 + (size_t)bh * TT;
    #pragma unroll 2
    for (int it = 0; it < 32; ++it) {
        int task = it * 256 + tid;
        int t = thalf * 512 + (task >> 4), dp = task & 15;
        float qv = qsp[t];
        float u = (qv - mnv) * inv127v;
        int i = (int)floorf(u) - 1;
        i = i < 0 ? 0 : (i > NND - 4 ? NND - 4 : i);
        float s = u - (float)i;
        float s1 = s - 1.f, s2 = s - 2.f, s3 = s - 3.f;
        float w0 = -s1 * s2 * s3 * (1.f / 6.f);
        float w1 = s * s2 * s3 * 0.5f;
        float w2 = -s * s1 * s3 * 0.5f;
        float w3 = s * s1 * s2 * (1.f / 6.f);
        const float* base = &nodes[i * NS];
        float4 v0 = *(const float4*)(base + 4 * dp);
        float4 v1 = *(const float4*)(base + NS + 4 * dp);
        float4 v2 = *(const float4*)(base + 2 * NS + 4 * dp);
        float4 v3 = *(const float4*)(base + 3 * NS + 4 * dp);
        float zz = w0 * base[64] + w1 * base[NS + 64] + w2 * base[2 * NS + 64] + w3 * base[3 * NS + 64];
        float ox = w0 * v0.x + w1 * v1.x + w2 * v2.x + w3 * v3.x;
        float oy = w0 * v0.y + w1 * v1.y + w2 * v2.y + w3 * v3.y;
        float oz = w0 * v0.z + w1 * v1.z + w2 * v2.z + w3 * v3.z;
        float ow = w0 * v0.w + w1 * v1.w + w2 * v2.w + w3 * v3.w;
        float rz = __builtin_amdgcn_rcpf(zz);
        uint2 st;
        st.x = pack2rne(ox * rz, oy * rz);
        st.y = pack2rne(oz * rz, ow * rz);
        int row = b * TT + t;
        int col = h * 64 + 4 * dp;
        int p = (col >> 3) ^ (row & 7);
        *(uint2*)&attb[(size_t)row * DDIM + p * 8 + (col & 7)] = st;
    }
}

// ---- K4: GEMM2 y = x + attb@WpT + bp, bf16 out. Tile 128 x 64, BK=64. ---------
__global__ __launch_bounds__(256) void gemm2_kernel(
    const unsigned short* __restrict__ A, const unsigned short* __restrict__ B,
    const float* __restrict__ bias, const float* __restrict__ x,
    unsigned short* __restrict__ yb)
{
    __shared__ __align__(16) unsigned short smem[12288];   // sA 8192 | sB 4096
    unsigned short* sA = smem;
    unsigned short* sB = smem + 8192;
    const int tid = threadIdx.x, lane = tid & 63, wave = tid >> 6;
    const int l15 = lane & 15, quad = lane >> 4;
    const int col0 = blockIdx.x * 64, row0 = blockIdx.y * 128;

    facc acc[2][4];
    #pragma unroll
    for (int i = 0; i < 2; ++i)
        #pragma unroll
        for (int j = 0; j < 4; ++j) { acc[i][j][0]=0.f; acc[i][j][1]=0.f; acc[i][j][2]=0.f; acc[i][j][3]=0.f; }

    for (int k0 = 0; k0 < 512; k0 += 64) {
        #pragma unroll
        for (int it = 0; it < 4; ++it) {
            int g = it * 256 + tid;
            int r = g >> 3, kg = g & 7;
            gl2lds16(A + (size_t)(row0 + r) * 512 + k0 + kg * 8, &sA[g * 8]);
        }
        #pragma unroll
        for (int it = 0; it < 2; ++it) {
            int g = it * 256 + tid;
            int r = g >> 3, kg = g & 7;
            gl2lds16(B + (size_t)(col0 + r) * 512 + k0 + kg * 8, &sB[g * 8]);
        }
        __syncthreads();
        #pragma unroll
        for (int ks_ = 0; ks_ < 2; ++ks_) {
            int slot = (ks_ * 4 + quad) ^ (l15 & 7);
            bfrag a[2], b[4];
            #pragma unroll
            for (int i = 0; i < 2; ++i)
                a[i] = *(const bfrag*)&sA[(wave * 32 + i * 16 + l15) * 64 + slot * 8];
            #pragma unroll
            for (int nt = 0; nt < 4; ++nt)
                b[nt] = *(const bfrag*)&sB[(nt * 16 + l15) * 64 + slot * 8];
            #pragma unroll
            for (int i = 0; i < 2; ++i)
                #pragma unroll
                for (int nt = 0; nt < 4; ++nt)
                    acc[i][nt] = __builtin_amdgcn_mfma_f32_16x16x32_bf16(a[i], b[nt], acc[i][nt], 0, 0, 0);
        }
        __syncthreads();
    }
    float bvv[4];
    #pragma unroll
    for (int nt = 0; nt < 4; ++nt) bvv[nt] = bias[col0 + nt * 16 + l15];
    unsigned short* yT = smem;   // [row][col] stride 72
    #pragma unroll
    for (int i = 0; i < 2; ++i) {
        #pragma unroll
        for (int nt = 0; nt < 4; ++nt) {
            int col = nt * 16 + l15;
            #pragma unroll
            for (int r = 0; r < 4; ++r) {
                int row = wave * 32 + i * 16 + quad * 4 + r;
                float xv = x[(size_t)(row0 + row) * DDIM + col0 + col];
                float y = acc[i][nt][r] + bvv[nt] + xv;
                yT[row * 72 + col] = (unsigned short)bfrne(y);
            }
        }
    }
    __syncthreads();
    #pragma unroll
    for (int it = 0; it < 4; ++it) {
        int task = it * 256 + tid;
        int row = task >> 3, seg = task & 7;
        uint4 v = *(const uint4*)&yT[row * 72 + seg * 8];
        *(uint4*)(yb + (size_t)(row0 + row) * DDIM + col0 + seg * 8) = v;
    }
}

// ---- K5: LayerNorm over bf16 y ------------------------------------------------
__global__ __launch_bounds__(256) void ln_kernel(
    const unsigned short* __restrict__ yb, const float* __restrict__ g,
    const float* __restrict__ bet, float* __restrict__ out)
{
    const int tid = threadIdx.x, lane = tid & 63, wave = tid >> 6;
    const int row = blockIdx.x * 4 + wave;
    uint4 v = *(const uint4*)(yb + (size_t)row * DDIM + lane * 8);
    float y[8];
    y[0] = __uint_as_float(v.x << 16); y[1] = __uint_as_float(v.x & 0xffff0000u);
    y[2] = __uint_as_float(v.y << 16); y[3] = __uint_as_float(v.y & 0xffff0000u);
    y[4] = __uint_as_float(v.z << 16); y[5] = __uint_as_float(v.z & 0xffff0000u);
    y[6] = __uint_as_float(v.w << 16); y[7] = __uint_as_float(v.w & 0xffff0000u);
    float s = 0.f, s2 = 0.f;
    #pragma unroll
    for (int i = 0; i < 8; ++i) { s += y[i]; s2 = fmaf(y[i], y[i], s2); }
    #pragma unroll
    for (int off = 32; off > 0; off >>= 1) {
        s += __shfl_xor(s, off);
        s2 += __shfl_xor(s2, off);
    }
    float mu = s * (1.f / 512.f);
    float var = s2 * (1.f / 512.f) - mu * mu;
    float inv = rsqrtf(var + 1e-5f);
    const float4* gp = (const float4*)(g + lane * 8);
    const float4* bp = (const float4*)(bet + lane * 8);
    float4 g0 = gp[0], g1 = gp[1], b0 = bp[0], b1 = bp[1];
    float4 o0, o1;
    o0.x = (y[0] - mu) * inv * g0.x + b0.x; o0.y = (y[1] - mu) * inv * g0.y + b0.y;
    o0.z = (y[2] - mu) * inv * g0.z + b0.z; o0.w = (y[3] - mu) * inv * g0.w + b0.w;
    o1.x = (y[4] - mu) * inv * g1.x + b1.x; o1.y = (y[5] - mu) * inv * g1.y + b1.y;
    o1.z = (y[6] - mu) * inv * g1.z + b1.z; o1.w = (y[7] - mu) * inv * g1.w + b1.w;
    float4* op = (float4*)(out + (size_t)row * DDIM);
    op[lane * 2] = o0; op[lane * 2 + 1] = o1;
}

// ---- launch -------------------------------------------------------------------
extern "C" void kernel_launch(void* const* d_in, const int* in_sizes, int n_in,
                              void* d_out, int out_size, void* d_ws, size_t ws_size,
                              hipStream_t stream)
{
    const float* x    = (const float*)d_in[0];
    const float* Wq   = (const float*)d_in[1];
    const float* bq   = (const float*)d_in[2];
    const float* Wk   = (const float*)d_in[3];
    const float* bk   = (const float*)d_in[4];
    const float* Wp   = (const float*)d_in[5];
    const float* bp   = (const float*)d_in[6];
    const float* wm   = (const float*)d_in[7];
    const float* ln_g = (const float*)d_in[8];
    const float* ln_b = (const float*)d_in[9];
    float* out = (float*)d_out;

    float* ws = (float*)d_ws;
    float*          qsb2 = ws;                                    // 64
    unsigned short* vq2b = (unsigned short*)(ws + 64);            // 2048 f
    unsigned short* WkT  = (unsigned short*)(ws + 2112);          // 131072 f
    unsigned short* WpT  = (unsigned short*)(ws + 133184);        // 131072 f
    unsigned short* xb   = (unsigned short*)(ws + 264256);        // 2097152 f
    unsigned short* kxTg = (unsigned short*)(ws + 2361408);       // 2097152 f
    float*          qs2  = ws + 4458560;                          // 65536
    float*          ks2  = ws + 4524096;                          // 65536
    unsigned short* attb = (unsigned short*)(ws + 4589632);       // 2097152 f
    unsigned short* yb   = xb;   // xb dead after gemm1; reuse for y

    prepare_kernel<<<2192, 256, 0, stream>>>(x, Wk, Wp, Wq, bq, wm,
                                             xb, WkT, WpT, vq2b, qsb2);
    gemm1_kernel<<<dim3(8, 64), 256, 0, stream>>>(xb, WkT, bk, kxTg, ks2, wm,
                                                  vq2b, qsb2, qs2);
    attn_kernel<<<128, 256, 0, stream>>>(kxTg, qs2, ks2, attb);
    gemm2_kernel<<<dim3(8, 64), 256, 0, stream>>>(attb, WpT, bp, x, yb);
    ln_kernel<<<2048, 256, 0, stream>>>(yb, ln_g, ln_b, out);
}

// Round 8
// 151.136 us; speedup vs baseline: 2.2693x; 1.0132x over previous
//
#include <hip/hip_runtime.h>
#include <cstddef>

#define TT 1024
#define DDIM 512
#define HH 8
#define NND 128          // interpolation nodes per (b,h)
#define NS 68            // node LDS row stride (floats): 64 d + Z at [64]

typedef __attribute__((ext_vector_type(8))) short bfrag;   // 8 bf16 (4 VGPRs)
typedef __attribute__((ext_vector_type(4))) float facc;    // 4 fp32 acc

#define SC2   2.8853900817779268f   // 2*log2(e)
#define L2E   1.4426950408889634f

static __device__ __forceinline__ unsigned bfrne(float f) {
    unsigned u = __float_as_uint(f);
    return (u + 0x7fffu + ((u >> 16) & 1u)) >> 16;
}
static __device__ __forceinline__ unsigned pack2rne(float a, float b) {
    return bfrne(a) | (bfrne(b) << 16);
}
static __device__ __forceinline__ unsigned pack2hu(float a, float b) {
    return ((__float_as_uint(a) + 0x8000u) >> 16) |
           ((__float_as_uint(b) + 0x8000u) & 0xffff0000u);
}
static __device__ __forceinline__ void gl2lds16(const void* g, void* l) {
    __builtin_amdgcn_global_load_lds(
        (const __attribute__((address_space(1))) unsigned int*)g,
        (__attribute__((address_space(3))) unsigned int*)l, 16, 0, 0);
}
// w(z2) = exp(tanh(z)) with z2 = 2*log2e*z pre-scaled
static __device__ __forceinline__ float wfun(float z2) {
    float t = __builtin_amdgcn_exp2f(z2);
    float r = __builtin_amdgcn_rcpf(t + 1.f);
    return __builtin_amdgcn_exp2f(fmaf(r, -2.f * L2E, L2E));
}

// ---- K1: fused prepare ---------------------------------------------------------
__global__ __launch_bounds__(256) void prepare_kernel(
    const float* __restrict__ x, const float* __restrict__ Wk,
    const float* __restrict__ Wp, const float* __restrict__ Wq,
    const float* __restrict__ bq, const float* __restrict__ wm,
    unsigned short* __restrict__ xb, unsigned short* __restrict__ WkT,
    unsigned short* __restrict__ WpT, unsigned short* __restrict__ vq2b,
    float* __restrict__ qsb2)
{
    const int bx = blockIdx.x, tid = threadIdx.x;
    if (bx < 2048) {
        const int lane = tid & 63, wave = tid >> 6;
        const int row = bx * 4 + wave;
        const float4* xr = (const float4*)(x + (size_t)row * DDIM);
        float4 x0 = xr[lane * 2], x1 = xr[lane * 2 + 1];
        uint4 st;
        st.x = pack2rne(x0.x, x0.y); st.y = pack2rne(x0.z, x0.w);
        st.z = pack2rne(x1.x, x1.y); st.w = pack2rne(x1.z, x1.w);
        int p = lane ^ (row & 7);
        *(uint4*)(xb + (size_t)row * DDIM + p * 8) = st;
    } else if (bx < 2176) {
        int idx = bx - 2048;
        const float* src = (idx & 64) ? Wp : Wk;
        unsigned short* dst = (idx & 64) ? WpT : WkT;
        idx &= 63;
        const int n0 = (idx & 7) * 64, k0 = (idx >> 3) * 64;
        __shared__ float sT[64][65];
        #pragma unroll
        for (int it = 0; it < 4; ++it) {
            int task = it * 256 + tid;
            int kr = task >> 4, c4 = (task & 15) * 4;
            float4 v = *(const float4*)(src + (size_t)(k0 + kr) * DDIM + n0 + c4);
            sT[kr][c4] = v.x; sT[kr][c4 + 1] = v.y; sT[kr][c4 + 2] = v.z; sT[kr][c4 + 3] = v.w;
        }
        __syncthreads();
        #pragma unroll
        for (int it = 0; it < 2; ++it) {
            int task = it * 256 + tid;
            int n = task >> 3, kg = task & 7;
            unsigned u[4];
            #pragma unroll
            for (int jj = 0; jj < 4; ++jj)
                u[jj] = pack2rne(sT[kg * 8 + jj * 2][n], sT[kg * 8 + jj * 2 + 1][n]);
            int p = ((k0 >> 3) + kg) ^ (n & 7);
            uint4 st; st.x = u[0]; st.y = u[1]; st.z = u[2]; st.w = u[3];
            *(uint4*)(dst + (size_t)(n0 + n) * DDIM + p * 8) = st;
        }
    } else {
        int idx = (bx - 2176) * 256 + tid;   // 0..4095
        int h = idx >> 9, d = idx & 511;
        float s = 0.f;
        #pragma unroll 8
        for (int j = 0; j < 64; ++j)
            s = fmaf(Wq[(size_t)d * DDIM + h * 64 + j], wm[64 + j], s);
        vq2b[h * DDIM + d] = (unsigned short)bfrne(s * SC2);
        if (idx < HH) {
            float sb = 0.f;
            for (int j = 0; j < 64; ++j)
                sb = fmaf(bq[idx * 64 + j], wm[64 + j], sb);
            qsb2[idx] = sb * SC2;
        }
    }
}

// ---- K2: GEMM1 kx = xb @ WkT + bk. Tile 128 t x 128 n (2 heads), BK=64. -------
// grid (64 row-tiles, 4 head-pairs): blockIdx.x fastest -> all 4 col-blocks of a
// row-tile share bid%8 (same XCD) -> A tile fetched ~once into that L2.
// Fused: qs2 via extra MFMA (vq2b B-frag); ks2 reduction; kxT transpose per head.
__global__ __launch_bounds__(256) void gemm1_kernel(
    const unsigned short* __restrict__ A, const unsigned short* __restrict__ B,
    const float* __restrict__ bias, unsigned short* __restrict__ kxTg,
    float* __restrict__ ks2, const float* __restrict__ wm,
    const unsigned short* __restrict__ vq2b, const float* __restrict__ qsb2,
    float* __restrict__ qs2)
{
    __shared__ __align__(16) unsigned short smem[17408]; // K: sA 8192|sB 8192; epi: eT 2x8704
    unsigned short* sA = smem;
    unsigned short* sB = smem + 8192;
    const int tid = threadIdx.x, lane = tid & 63, wave = tid >> 6;
    const int l15 = lane & 15, quad = lane >> 4;
    const int wr = wave >> 1, wc = wave & 1;
    const int row0 = blockIdx.x * 128, colpair = blockIdx.y;
    const int h = colpair * 2 + wc, n0 = colpair * 128;

    facc acc[4][4]; facc accq[4];
    #pragma unroll
    for (int i = 0; i < 4; ++i) {
        #pragma unroll
        for (int j = 0; j < 4; ++j) { acc[i][j][0]=0.f; acc[i][j][1]=0.f; acc[i][j][2]=0.f; acc[i][j][3]=0.f; }
        accq[i][0]=0.f; accq[i][1]=0.f; accq[i][2]=0.f; accq[i][3]=0.f;
    }

    for (int k0 = 0; k0 < 512; k0 += 64) {
        #pragma unroll
        for (int it = 0; it < 4; ++it) {
            int g = it * 256 + tid;
            int r = g >> 3, kg = g & 7;
            gl2lds16(A + (size_t)(row0 + r) * 512 + k0 + kg * 8, &sA[g * 8]);
            gl2lds16(B + (size_t)(n0 + r) * 512 + k0 + kg * 8, &sB[g * 8]);
        }
        __syncthreads();
        #pragma unroll
        for (int ks_ = 0; ks_ < 2; ++ks_) {
            int slot = (ks_ * 4 + quad) ^ (l15 & 7);
            bfrag a[4], b[4];
            #pragma unroll
            for (int i = 0; i < 4; ++i) {
                a[i] = *(const bfrag*)&sA[(wr * 64 + i * 16 + l15) * 64 + slot * 8];
                b[i] = *(const bfrag*)&sB[(wc * 64 + i * 16 + l15) * 64 + slot * 8];
            }
            bfrag bvq = *(const bfrag*)(vq2b + h * 512 + k0 + ks_ * 32 + quad * 8);
            #pragma unroll
            for (int i = 0; i < 4; ++i) {
                #pragma unroll
                for (int nt = 0; nt < 4; ++nt)
                    acc[i][nt] = __builtin_amdgcn_mfma_f32_16x16x32_bf16(a[i], b[nt], acc[i][nt], 0, 0, 0);
                accq[i] = __builtin_amdgcn_mfma_f32_16x16x32_bf16(a[i], bvq, accq[i], 0, 0, 0);
            }
        }
        __syncthreads();
    }

    // ---- epilogue: bias, qs2/ks2, per-head LDS transpose, coalesced stores ----
    const int bb = row0 >> 10, t0 = row0 & 1023;
    const float qsbh = qsb2[h];
    float bvv[4], wmv[4];
    #pragma unroll
    for (int nt = 0; nt < 4; ++nt) {
        bvv[nt] = bias[h * 64 + nt * 16 + l15];
        wmv[nt] = wm[nt * 16 + l15] * SC2;
    }
    float part[4][4];
    #pragma unroll
    for (int i = 0; i < 4; ++i)
        #pragma unroll
        for (int r = 0; r < 4; ++r) part[i][r] = 0.f;

    unsigned short* eT = smem + wc * 8704;   // [d][t] stride 136, per head
    #pragma unroll
    for (int i = 0; i < 4; ++i) {
        int tr = wr * 64 + i * 16 + quad * 4;
        #pragma unroll
        for (int nt = 0; nt < 4; ++nt) {
            int d = nt * 16 + l15;
            float v0 = acc[i][nt][0] + bvv[nt], v1 = acc[i][nt][1] + bvv[nt];
            float v2 = acc[i][nt][2] + bvv[nt], v3 = acc[i][nt][3] + bvv[nt];
            part[i][0] = fmaf(wmv[nt], v0, part[i][0]);
            part[i][1] = fmaf(wmv[nt], v1, part[i][1]);
            part[i][2] = fmaf(wmv[nt], v2, part[i][2]);
            part[i][3] = fmaf(wmv[nt], v3, part[i][3]);
            *(unsigned*)&eT[d * 136 + tr]     = pack2rne(v0, v1);
            *(unsigned*)&eT[d * 136 + tr + 2] = pack2rne(v2, v3);
        }
    }
    #pragma unroll
    for (int i = 0; i < 4; ++i)
        #pragma unroll
        for (int r = 0; r < 4; ++r) {
            float p = part[i][r];
            p += __shfl_xor(p, 1); p += __shfl_xor(p, 2);
            p += __shfl_xor(p, 4); p += __shfl_xor(p, 8);
            if (l15 == 0) {
                size_t o = (size_t)(bb * HH + h) * TT + t0 + wr * 64 + i * 16 + quad * 4 + r;
                ks2[o] = p;
                qs2[o] = accq[i][r] + qsbh;
            }
        }
    __syncthreads();
    #pragma unroll
    for (int it = 0; it < 8; ++it) {
        int task = it * 256 + tid;
        int hh = task >> 10, rem = task & 1023;
        int col = rem >> 4, seg = rem & 15;
        uint4 v = *(const uint4*)&smem[hh * 8704 + col * 136 + seg * 8];
        int hg = colpair * 2 + hh;
        int g = (t0 >> 3) + seg;
        int p = g ^ (col & 7);
        *(uint4*)(kxTg + ((size_t)(bb * HH + hg) * 64 + col) * TT + p * 8) = v;
    }
}

// ---- K3: node-curve attention + fused cubic interp ----------------------------
// grid (64 bh, 2 t-half): both t-halves of a bh share bid%8 -> same XCD L2.
__global__ __launch_bounds__(256) void attn_kernel(
    const unsigned short* __restrict__ kxTg, const float* __restrict__ qs2,
    const float* __restrict__ ks2, unsigned short* __restrict__ attb)
{
    __shared__ __align__(16) unsigned short kxT[64 * 256];  // 32 KB
    __shared__ float ksc[1024];
    __shared__ float redl[8];
    __shared__ __align__(16) float nodes[NND * NS];         // 34 KB
    const int bh = blockIdx.x, thalf = blockIdx.y;
    const int b = bh >> 3, h = bh & 7;
    const int tid = threadIdx.x, lane = tid & 63, wave = tid >> 6;
    const int l15 = lane & 15, quad = lane >> 4;

    ((float4*)ksc)[tid] = ((const float4*)(ks2 + (size_t)bh * TT))[tid];
    float4 q4 = ((const float4*)(qs2 + (size_t)bh * TT))[tid];
    float mn = fminf(fminf(q4.x, q4.y), fminf(q4.z, q4.w));
    float mx = fmaxf(fmaxf(q4.x, q4.y), fmaxf(q4.z, q4.w));
    #pragma unroll
    for (int off = 32; off > 0; off >>= 1) {
        mn = fminf(mn, __shfl_xor(mn, off));
        mx = fmaxf(mx, __shfl_xor(mx, off));
    }
    if (lane == 0) { redl[wave] = mn; redl[4 + wave] = mx; }
    __syncthreads();
    const float mnv = fminf(fminf(redl[0], redl[1]), fminf(redl[2], redl[3]));
    const float mxv = fmaxf(fmaxf(redl[4], redl[5]), fmaxf(redl[6], redl[7]));
    const float h2v = (mxv - mnv) * (1.f / 127.f);
    const float inv127v = 127.f / fmaxf(mxv - mnv, 1e-12f);
    const float zA = mnv + (wave * 16 + l15) * h2v;
    const float zB = zA + 64.f * h2v;

    const unsigned short* kxbase = kxTg + (size_t)bh * 64 * TT;
    facc acc[2][4]; facc accZ[2];
    #pragma unroll
    for (int g = 0; g < 2; ++g) {
        #pragma unroll
        for (int i = 0; i < 4; ++i) { acc[g][i][0]=0.f; acc[g][i][1]=0.f; acc[g][i][2]=0.f; acc[g][i][3]=0.f; }
        accZ[g][0]=0.f; accZ[g][1]=0.f; accZ[g][2]=0.f; accZ[g][3]=0.f;
    }
    bfrag ones;
    #pragma unroll
    for (int j = 0; j < 8; ++j) ones[j] = (short)0x3F80;

    for (int ck = 0; ck < 4; ++ck) {
        #pragma unroll
        for (int it = 0; it < 8; ++it) {
            int g = it * 256 + tid;
            int d = g >> 5, j = g & 31;
            gl2lds16(kxbase + (size_t)d * TT + ck * 256 + j * 8, &kxT[g * 8]);
        }
        __syncthreads();
        #pragma unroll
        for (int kst = 0; kst < 8; ++kst) {
            const float* kvp = &ksc[ck * 256 + kst * 32 + quad * 8];
            float4 kv0 = *(const float4*)kvp;
            float4 kv1 = *(const float4*)(kvp + 4);
            int slot = (kst * 4 + quad) ^ (l15 & 7);
            bfrag bf_[4];
            #pragma unroll
            for (int dt = 0; dt < 4; ++dt)
                bf_[dt] = *(const bfrag*)&kxT[(dt * 16 + l15) * 256 + slot * 8];
            #pragma unroll
            for (int g = 0; g < 2; ++g) {
                float z = g ? zB : zA;
                union { unsigned u[4]; bfrag f; } afu;
                afu.u[0] = pack2hu(wfun(z + kv0.x), wfun(z + kv0.y));
                afu.u[1] = pack2hu(wfun(z + kv0.z), wfun(z + kv0.w));
                afu.u[2] = pack2hu(wfun(z + kv1.x), wfun(z + kv1.y));
                afu.u[3] = pack2hu(wfun(z + kv1.z), wfun(z + kv1.w));
                #pragma unroll
                for (int dt = 0; dt < 4; ++dt)
                    acc[g][dt] = __builtin_amdgcn_mfma_f32_16x16x32_bf16(afu.f, bf_[dt], acc[g][dt], 0, 0, 0);
                accZ[g] = __builtin_amdgcn_mfma_f32_16x16x32_bf16(afu.f, ones, accZ[g], 0, 0, 0);
            }
        }
        __syncthreads();
    }
    #pragma unroll
    for (int g = 0; g < 2; ++g) {
        #pragma unroll
        for (int r = 0; r < 4; ++r) {
            int node = g * 64 + wave * 16 + quad * 4 + r;
            #pragma unroll
            for (int dt = 0; dt < 4; ++dt)
                nodes[node * NS + dt * 16 + l15] = acc[g][dt][r];
            if (l15 == 0) nodes[node * NS + 64] = accZ[g][r];
        }
    }
    __syncthreads();

    const float* qsp = qs2 + (size_t)bh * TT;
    #pragma unroll 2
    for (int it = 0; it < 32; ++it) {
        int task = it * 256 + tid;
        int t = thalf * 512 + (task >> 4), dp = task & 15;
        float qv = qsp[t];
        float u = (qv - mnv) * inv127v;
        int i = (int)floorf(u) - 1;
        i = i < 0 ? 0 : (i > NND - 4 ? NND - 4 : i);
        float s = u - (float)i;
        float s1 = s - 1.f, s2 = s - 2.f, s3 = s - 3.f;
        float w0 = -s1 * s2 * s3 * (1.f / 6.f);
        float w1 = s * s2 * s3 * 0.5f;
        float w2 = -s * s1 * s3 * 0.5f;
        float w3 = s * s1 * s2 * (1.f / 6.f);
        const float* base = &nodes[i * NS];
        float4 v0 = *(const float4*)(base + 4 * dp);
        float4 v1 = *(const float4*)(base + NS + 4 * dp);
        float4 v2 = *(const float4*)(base + 2 * NS + 4 * dp);
        float4 v3 = *(const float4*)(base + 3 * NS + 4 * dp);
        float zz = w0 * base[64] + w1 * base[NS + 64] + w2 * base[2 * NS + 64] + w3 * base[3 * NS + 64];
        float ox = w0 * v0.x + w1 * v1.x + w2 * v2.x + w3 * v3.x;
        float oy = w0 * v0.y + w1 * v1.y + w2 * v2.y + w3 * v3.y;
        float oz = w0 * v0.z + w1 * v1.z + w2 * v2.z + w3 * v3.z;
        float ow = w0 * v0.w + w1 * v1.w + w2 * v2.w + w3 * v3.w;
        float rz = __builtin_amdgcn_rcpf(zz);
        uint2 st;
        st.x = pack2rne(ox * rz, oy * rz);
        st.y = pack2rne(oz * rz, ow * rz);
        int row = b * TT + t;
        int col = h * 64 + 4 * dp;
        int p = (col >> 3) ^ (row & 7);
        *(uint2*)&attb[(size_t)row * DDIM + p * 8 + (col & 7)] = st;
    }
}

// ---- K4: GEMM2 proj = attb @ WpT + bp, bf16 out (no residual). 128x128. -------
__global__ __launch_bounds__(256) void gemm2_kernel(
    const unsigned short* __restrict__ A, const unsigned short* __restrict__ B,
    const float* __restrict__ bias, unsigned short* __restrict__ yb)
{
    __shared__ __align__(16) unsigned short smem[17408]; // K: sA|sB; epi: yT 128x136
    unsigned short* sA = smem;
    unsigned short* sB = smem + 8192;
    const int tid = threadIdx.x, lane = tid & 63, wave = tid >> 6;
    const int l15 = lane & 15, quad = lane >> 4;
    const int wr = wave >> 1, wc = wave & 1;
    const int row0 = blockIdx.x * 128, col0 = blockIdx.y * 128;

    facc acc[4][4];
    #pragma unroll
    for (int i = 0; i < 4; ++i)
        #pragma unroll
        for (int j = 0; j < 4; ++j) { acc[i][j][0]=0.f; acc[i][j][1]=0.f; acc[i][j][2]=0.f; acc[i][j][3]=0.f; }

    for (int k0 = 0; k0 < 512; k0 += 64) {
        #pragma unroll
        for (int it = 0; it < 4; ++it) {
            int g = it * 256 + tid;
            int r = g >> 3, kg = g & 7;
            gl2lds16(A + (size_t)(row0 + r) * 512 + k0 + kg * 8, &sA[g * 8]);
            gl2lds16(B + (size_t)(col0 + r) * 512 + k0 + kg * 8, &sB[g * 8]);
        }
        __syncthreads();
        #pragma unroll
        for (int ks_ = 0; ks_ < 2; ++ks_) {
            int slot = (ks_ * 4 + quad) ^ (l15 & 7);
            bfrag a[4], b[4];
            #pragma unroll
            for (int i = 0; i < 4; ++i) {
                a[i] = *(const bfrag*)&sA[(wr * 64 + i * 16 + l15) * 64 + slot * 8];
                b[i] = *(const bfrag*)&sB[(wc * 64 + i * 16 + l15) * 64 + slot * 8];
            }
            #pragma unroll
            for (int i = 0; i < 4; ++i)
                #pragma unroll
                for (int nt = 0; nt < 4; ++nt)
                    acc[i][nt] = __builtin_amdgcn_mfma_f32_16x16x32_bf16(a[i], b[nt], acc[i][nt], 0, 0, 0);
        }
        __syncthreads();
    }
    float bvv[4];
    #pragma unroll
    for (int nt = 0; nt < 4; ++nt) bvv[nt] = bias[col0 + wc * 64 + nt * 16 + l15];
    unsigned short* yT = smem;   // [row][col] stride 136
    #pragma unroll
    for (int i = 0; i < 4; ++i) {
        #pragma unroll
        for (int nt = 0; nt < 4; ++nt) {
            int col = wc * 64 + nt * 16 + l15;
            #pragma unroll
            for (int r = 0; r < 4; ++r) {
                int row = wr * 64 + i * 16 + quad * 4 + r;
                yT[row * 136 + col] = (unsigned short)bfrne(acc[i][nt][r] + bvv[nt]);
            }
        }
    }
    __syncthreads();
    #pragma unroll
    for (int it = 0; it < 8; ++it) {
        int task = it * 256 + tid;
        int row = task >> 4, seg = task & 15;
        uint4 v = *(const uint4*)&yT[row * 136 + seg * 8];
        *(uint4*)(yb + (size_t)(row0 + row) * DDIM + col0 + seg * 8) = v;
    }
}

// ---- K5: residual (bf16 xb) + LayerNorm ---------------------------------------
__global__ __launch_bounds__(256) void ln_kernel(
    const unsigned short* __restrict__ yb, const unsigned short* __restrict__ xb,
    const float* __restrict__ g, const float* __restrict__ bet,
    float* __restrict__ out)
{
    const int tid = threadIdx.x, lane = tid & 63, wave = tid >> 6;
    const int row = blockIdx.x * 4 + wave;
    uint4 pv = *(const uint4*)(yb + (size_t)row * DDIM + lane * 8);
    int pgr = lane ^ (row & 7);                    // unswizzle xb granule
    uint4 xv = *(const uint4*)(xb + (size_t)row * DDIM + pgr * 8);
    float y[8];
    const unsigned* pu = (const unsigned*)&pv;
    const unsigned* xu = (const unsigned*)&xv;
    #pragma unroll
    for (int j = 0; j < 4; ++j) {
        y[2*j]   = __uint_as_float(pu[j] << 16)        + __uint_as_float(xu[j] << 16);
        y[2*j+1] = __uint_as_float(pu[j] & 0xffff0000u) + __uint_as_float(xu[j] & 0xffff0000u);
    }
    float s = 0.f, s2 = 0.f;
    #pragma unroll
    for (int i = 0; i < 8; ++i) { s += y[i]; s2 = fmaf(y[i], y[i], s2); }
    #pragma unroll
    for (int off = 32; off > 0; off >>= 1) {
        s += __shfl_xor(s, off);
        s2 += __shfl_xor(s2, off);
    }
    float mu = s * (1.f / 512.f);
    float var = s2 * (1.f / 512.f) - mu * mu;
    float inv = rsqrtf(var + 1e-5f);
    const float4* gp = (const float4*)(g + lane * 8);
    const float4* bp = (const float4*)(bet + lane * 8);
    float4 g0 = gp[0], g1 = gp[1], b0 = bp[0], b1 = bp[1];
    float4 o0, o1;
    o0.x = (y[0] - mu) * inv * g0.x + b0.x; o0.y = (y[1] - mu) * inv * g0.y + b0.y;
    o0.z = (y[2] - mu) * inv * g0.z + b0.z; o0.w = (y[3] - mu) * inv * g0.w + b0.w;
    o1.x = (y[4] - mu) * inv * g1.x + b1.x; o1.y = (y[5] - mu) * inv * g1.y + b1.y;
    o1.z = (y[6] - mu) * inv * g1.z + b1.z; o1.w = (y[7] - mu) * inv * g1.w + b1.w;
    float4* op = (float4*)(out + (size_t)row * DDIM);
    op[lane * 2] = o0; op[lane * 2 + 1] = o1;
}

// ---- launch -------------------------------------------------------------------
extern "C" void kernel_launch(void* const* d_in, const int* in_sizes, int n_in,
                              void* d_out, int out_size, void* d_ws, size_t ws_size,
                              hipStream_t stream)
{
    const float* x    = (const float*)d_in[0];
    const float* Wq   = (const float*)d_in[1];
    const float* bq   = (const float*)d_in[2];
    const float* Wk   = (const float*)d_in[3];
    const float* bk   = (const float*)d_in[4];
    const float* Wp   = (const float*)d_in[5];
    const float* bp   = (const float*)d_in[6];
    const float* wm   = (const float*)d_in[7];
    const float* ln_g = (const float*)d_in[8];
    const float* ln_b = (const float*)d_in[9];
    float* out = (float*)d_out;

    float* ws = (float*)d_ws;
    float*          qsb2 = ws;                                    // 64
    unsigned short* vq2b = (unsigned short*)(ws + 64);            // 2048 f
    unsigned short* WkT  = (unsigned short*)(ws + 2112);          // 131072 f
    unsigned short* WpT  = (unsigned short*)(ws + 133184);        // 131072 f
    unsigned short* xb   = (unsigned short*)(ws + 264256);        // 2097152 f
    unsigned short* kxTg = (unsigned short*)(ws + 2361408);       // 2097152 f
    float*          qs2  = ws + 4458560;                          // 65536
    float*          ks2  = ws + 4524096;                          // 65536
    unsigned short* attb = (unsigned short*)(ws + 4589632);       // 2097152 f
    unsigned short* yb   = (unsigned short*)(ws + 6686784);       // 2097152 f

    prepare_kernel<<<2192, 256, 0, stream>>>(x, Wk, Wp, Wq, bq, wm,
                                             xb, WkT, WpT, vq2b, qsb2);
    gemm1_kernel<<<dim3(64, 4), 256, 0, stream>>>(xb, WkT, bk, kxTg, ks2, wm,
                                                  vq2b, qsb2, qs2);
    attn_kernel<<<dim3(64, 2), 256, 0, stream>>>(kxTg, qs2, ks2, attb);
    gemm2_kernel<<<dim3(64, 4), 256, 0, stream>>>(attb, WpT, bp, yb);
    ln_kernel<<<2048, 256, 0, stream>>>(yb, xb, ln_g, ln_b, out);
}